// Round 8
// baseline (9362935.938 us; speedup 1.0000x reference)
//
#include <hip/hip_runtime.h>
#include <hip/hip_bf16.h>
#include <math.h>

// GRU decoder: embed+relu -> gi GEMM (2-phase dbuf) -> same-XCD hidden-split GRU
// with half-batch pipelining (L2-scope flags, inv/wbl2 replay protocol) ->
// vocab projection (2-phase dbuf, bf16 logits aliased into d_out) -> log_softmax.

typedef __bf16 bf16x8 __attribute__((ext_vector_type(8)));
typedef float  f32x4  __attribute__((ext_vector_type(4)));
typedef unsigned short u16;
typedef u16 u16x8v __attribute__((ext_vector_type(8)));
typedef u16 u16x4v __attribute__((ext_vector_type(4)));

#define BTV (32L * 64 * 32000)
#define LDC2 64000L   // bf16 logit row stride inside d_out (half of a 128000B f32 row slot)

// ---- ws layout (bytes) ----
#define OFF_X    (0L)
#define SZ_X     (2048L * 256 * 2)
#define OFF_WIH  (OFF_X + SZ_X)
#define SZ_WIH   (1536L * 256 * 2)
#define OFF_WHH  (OFF_WIH + SZ_WIH)
#define SZ_WHH   (1536L * 512 * 2)
#define OFF_WOUT (OFF_WHH + SZ_WHH)
#define SZ_WOUT  (32000L * 512 * 2)
#define OFF_GI   (OFF_WOUT + SZ_WOUT)
#define SZ_GI    (2048L * 1536 * 4)
#define OFF_HS   (OFF_GI + SZ_GI)
#define SZ_HS    (2048L * 512 * 2)
#define OFF_FLG  (OFF_HS + SZ_HS)
#define SZ_FLG   (1024L)
#define OFF_EV   (OFF_FLG + SZ_FLG)
#define SZ_EV    (64L)
#define WS_NEED  (OFF_EV + SZ_EV)

__device__ __forceinline__ u16 f2bf(float f) {
  union { float f; unsigned u; } a; a.f = f;
  unsigned r = a.u + 0x7fffu + ((a.u >> 16) & 1u);
  return (u16)(r >> 16);
}

__device__ __forceinline__ float bf2f(u16 u) {
  union { unsigned u; float f; } a; a.u = ((unsigned)u) << 16;
  return a.f;
}

__device__ __forceinline__ void gload16(const void* g, void* l) {
  __builtin_amdgcn_global_load_lds(
      (const __attribute__((address_space(1))) unsigned int*)g,
      (__attribute__((address_space(3))) unsigned int*)l, 16, 0, 0);
}

// ---------------- cast f32 -> bf16 ----------------
extern "C" __global__ void k_cast(const float* __restrict__ s, u16* __restrict__ d, int n4) {
  int i = blockIdx.x * blockDim.x + threadIdx.x;
  int st = gridDim.x * blockDim.x;
  for (; i < n4; i += st) {
    float4 v = reinterpret_cast<const float4*>(s)[i];
    u16x4v o; o.x = f2bf(v.x); o.y = f2bf(v.y); o.z = f2bf(v.z); o.w = f2bf(v.w);
    reinterpret_cast<u16x4v*>(d)[i] = o;
  }
}

// ---------------- embed + relu -> X[t*32+b][256] bf16 ----------------
extern "C" __global__ void k_embed(const float* __restrict__ emb, const int* __restrict__ tgt,
                                   u16* __restrict__ X) {
  int idx = blockIdx.x * 256 + threadIdx.x;
  int row = idx >> 5;
  int c8  = (idx & 31) << 3;
  int t = row >> 5, b = row & 31;
  int token = (t == 0) ? 0 : tgt[b * 64 + t - 1];
  const float* e = emb + (long)token * 256 + c8;
  u16x8v o;
#pragma unroll
  for (int i = 0; i < 8; ++i) { float v = e[i]; o[i] = f2bf(v > 0.f ? v : 0.f); }
  *reinterpret_cast<u16x8v*>(X + (long)row * 256 + c8) = o;
}

// ---------------- flags (LLC write-through) + election vars init ----------------
extern "C" __global__ void k_init(unsigned* flags, unsigned* evars) {
  int i = threadIdx.x;
  if (i < 256) {
    unsigned z = 0u;
    asm volatile("global_store_dword %0, %1, off sc0 sc1"
                 :: "v"(flags + i), "v"(z) : "memory");
  }
  if (i < 10) atomicExch(&evars[i], i == 8 ? 0xFFFFFFFFu : 0u);
}

// ---------------- bf16 MFMA GEMM, C = A*B^T + bias, 2-phase LDS double-buffer ----------------
template <bool BF16OUT>
__global__ void __launch_bounds__(256)
k_gemm_t(const u16* __restrict__ A, const u16* __restrict__ B,
         const float* __restrict__ bias, float* __restrict__ C,
         u16* __restrict__ C2, int M, int N, int K, long ldc2) {
  __shared__ u16 At[2][4096];
  __shared__ u16 Bt[2][4096];
  int mt = M >> 7;
  int bn = blockIdx.x / mt, bm = blockIdx.x % mt;
  int tid = threadIdx.x, wave = tid >> 6, lane = tid & 63;
  int wr = wave >> 1, wc = wave & 1;
  f32x4 acc[4][4] = {};
  const u16* ga = A + (long)(bm * 128 + wave * 32 + (lane >> 2)) * K + ((lane & 3) << 3);
  const u16* gb = B + (long)(bn * 128 + wave * 32 + (lane >> 2)) * K + ((lane & 3) << 3);
  long k16 = 16L * K;
  // prologue stage
  {
    u16* la0 = &At[0][wave * 1024]; u16* lb0 = &Bt[0][wave * 1024];
    gload16(ga, la0); gload16(ga + k16, la0 + 512);
    gload16(gb, lb0); gload16(gb + k16, lb0 + 512);
  }
  asm volatile("s_waitcnt vmcnt(0)" ::: "memory");
  __syncthreads();
  int cur = 0;
  for (int k0 = 0; k0 < K; k0 += 32) {
    if (k0 + 32 < K) {
      int nb = cur ^ 1;
      u16* la0 = &At[nb][wave * 1024]; u16* lb0 = &Bt[nb][wave * 1024];
      gload16(ga + k0 + 32, la0); gload16(ga + k16 + k0 + 32, la0 + 512);
      gload16(gb + k0 + 32, lb0); gload16(gb + k16 + k0 + 32, lb0 + 512);
    }
    bf16x8 af[4], bfr[4];
#pragma unroll
    for (int mi = 0; mi < 4; ++mi)
      af[mi] = *reinterpret_cast<const bf16x8*>(
          &At[cur][(wr * 64 + mi * 16 + (lane & 15)) * 32 + ((lane >> 4) << 3)]);
#pragma unroll
    for (int ni = 0; ni < 4; ++ni)
      bfr[ni] = *reinterpret_cast<const bf16x8*>(
          &Bt[cur][(wc * 64 + ni * 16 + (lane & 15)) * 32 + ((lane >> 4) << 3)]);
#pragma unroll
    for (int mi = 0; mi < 4; ++mi)
#pragma unroll
      for (int ni = 0; ni < 4; ++ni)
        acc[mi][ni] = __builtin_amdgcn_mfma_f32_16x16x32_bf16(af[mi], bfr[ni], acc[mi][ni], 0, 0, 0);
    asm volatile("s_waitcnt vmcnt(0)" ::: "memory");
    __syncthreads();
    cur ^= 1;
  }
  int rb = bm * 128 + wr * 64 + ((lane >> 4) << 2);
  int cb = bn * 128 + wc * 64 + (lane & 15);
#pragma unroll
  for (int mi = 0; mi < 4; ++mi)
#pragma unroll
    for (int ni = 0; ni < 4; ++ni) {
      int col = cb + ni * 16;
      float bv = bias[col];
#pragma unroll
      for (int q = 0; q < 4; ++q) {
        int rr = rb + mi * 16 + q;
        if (BF16OUT) C2[(long)rr * ldc2 + col] = f2bf(acc[mi][ni][q] + bv);
        else         C[(long)rr * N + col] = acc[mi][ni][q] + bv;
      }
    }
}

// ---------------- same-XCD hidden-split GRU, half-batch pipelined ----------------
// 64 blocks launched; leader election picks one XCD, first 8 claimants work.
// Per step: two half-batch phases (b 0-15, 16-31); each half's flag handoff hides
// under the other half's compute. Flags at L2 scope (sc0); buffer_inv at start +
// buffer_wbl2 at end make graph replay safe.
extern "C" __global__ void __launch_bounds__(768, 1)
k_gru7(const float* __restrict__ gi, const u16* __restrict__ Whh,
       const float* __restrict__ bhh, const float* __restrict__ eh,
       u16* __restrict__ HS, float* __restrict__ outH,
       unsigned* flags, unsigned* evars) {
  __shared__ u16 Ah[16 * 512];          // swizzled half-batch h tile (16 KB, reused A/B)
  __shared__ float gh[3][2][16][66];    // gate partials (reused A/B)
  __shared__ int role_s;
  int tid = threadIdx.x, wave = tid >> 6, lane = tid & 63;
  if (tid == 0) {
    unsigned xcc;
    asm volatile("s_getreg_b32 %0, hwreg(20, 0, 32)" : "=s"(xcc));
    xcc &= 7u;
    unsigned arr = atomicAdd(&evars[xcc], 1u);
    if (arr == 7u) atomicCAS(&evars[8], 0xFFFFFFFFu, xcc);
    unsigned L = 0xFFFFFFFFu;
    for (int it = 0; it < (1 << 24) && L == 0xFFFFFFFFu; ++it) {
      asm volatile("global_load_dword %0, %1, off sc0 sc1\n\ts_waitcnt vmcnt(0)"
                   : "=v"(L) : "v"(evars + 8) : "memory");
    }
    int role = -1;
    if (L == xcc) {
      unsigned c = atomicAdd(&evars[9], 1u);
      if (c < 8u) role = (int)c;
    }
    role_s = role;
  }
  __syncthreads();
  int g = role_s;
  if (g < 0) return;
  // drop stale clean lines (prev-replay flags) from this XCD's L2
  if (tid == 0) asm volatile("buffer_inv sc1\n\ts_waitcnt vmcnt(0)" ::: "memory");
  __syncthreads();
  int j0 = g * 64;
  int gate = wave >> 2, uh = (wave >> 1) & 1, sig = wave & 1;
  bf16x8 barr[2][8];
  {
    const u16* wbase = Whh + (long)(gate * 512 + j0 + uh * 32) * 512 + sig * 256;
#pragma unroll
    for (int ut = 0; ut < 2; ++ut)
#pragma unroll
      for (int kt = 0; kt < 8; ++kt)
        barr[ut][kt] = *reinterpret_cast<const bf16x8*>(
            wbase + (long)(ut * 16 + (lane & 15)) * 512 + kt * 32 + ((lane >> 4) << 3));
  }
  int u = tid & 63;
  int bl0 = tid >> 6, bl1 = 12 + bl0;          // local batch rows (gh index)
  bool s1 = tid < 256;
  int bA0 = bl0, bA1 = bl1, bB0 = 16 + bl0, bB1 = 28 + bl1 - 12;  // bB1 = 28+bl0
  float bb0 = bhh[j0 + u], bb1 = bhh[512 + j0 + u], bb2 = bhh[1024 + j0 + u];
  float hpA0 = eh[bA0 * 512 + j0 + u];
  float hpA1 = s1 ? eh[bA1 * 512 + j0 + u] : 0.f;
  float hpB0 = eh[bB0 * 512 + j0 + u];
  float hpB1 = s1 ? eh[bB1 * 512 + j0 + u] : 0.f;
  const float* gpA0 = gi + (long)bA0 * 1536 + j0 + u;
  const float* gpA1 = gi + (long)bA1 * 1536 + j0 + u;
  const float* gpB0 = gi + (long)bB0 * 1536 + j0 + u;
  const float* gpB1 = gi + (long)bB1 * 1536 + j0 + u;
  u16* hsA0 = HS + (long)bA0 * 64 * 512 + j0 + u;
  u16* hsA1 = HS + (long)bA1 * 64 * 512 + j0 + u;
  u16* hsB0 = HS + (long)bB0 * 64 * 512 + j0 + u;
  u16* hsB1 = HS + (long)bB1 * 64 * 512 + j0 + u;
  // staging: tid<512, 2 chunks (rows 0-7 and 8-15 of the half), src advances 1KB/step
  char* ld0 = nullptr; char* ld1 = nullptr;
  const char* spA0 = nullptr; const char* spA1 = nullptr;
  const char* spB0 = nullptr; const char* spB1 = nullptr;
  if (tid < 512) {
    int r0 = tid >> 6, i0 = tid & 63, r1 = 8 + r0;
    ld0 = (char*)Ah + r0 * 1024 + ((i0 * 16) ^ ((r0 & 7) << 4));
    ld1 = (char*)Ah + r1 * 1024 + ((i0 * 16) ^ ((r1 & 7) << 4));
    spA0 = (const char*)HS + (long)r0 * 65536 + i0 * 16 - 1024;
    spA1 = (const char*)HS + (long)r1 * 65536 + i0 * 16 - 1024;
    spB0 = spA0 + 16L * 65536;
    spB1 = spA1 + 16L * 65536;
  }
  int r15 = lane & 15;
  int cbyte = sig * 512 + ((lane >> 4) << 4);
  int ucol = uh * 32 + r15;
  int brow = (lane >> 4) << 2;
  const float K1 = -1.44269504f, K2 = 2.88539009f;

  for (int t = 0; t < 64; ++t) {
    // ================= HALF A (b 0-15) =================
    if (t == 0) {
      if (tid < 256) {
#pragma unroll
        for (int l = 0; l < 4; ++l) {
          int n = l * 256 + tid; int row = n >> 6; int i = n & 63;
          const float* sp = eh + (row * 512 + i * 8);
          float4 aa = *reinterpret_cast<const float4*>(sp);
          float4 bb = *reinterpret_cast<const float4*>(sp + 4);
          u16x8v o8;
          o8[0] = f2bf(aa.x); o8[1] = f2bf(aa.y); o8[2] = f2bf(aa.z); o8[3] = f2bf(aa.w);
          o8[4] = f2bf(bb.x); o8[5] = f2bf(bb.y); o8[6] = f2bf(bb.z); o8[7] = f2bf(bb.w);
          *reinterpret_cast<u16x8v*>((char*)Ah + row * 1024 + ((i * 16) ^ ((row & 7) << 4))) = o8;
        }
      }
    } else {
      if (wave == 0) {
        const unsigned* fp = flags + (lane & 7) * 16;
        unsigned v;
        do {
          asm volatile("global_load_dword %0, %1, off sc0\n\ts_waitcnt vmcnt(0)"
                       : "=v"(v) : "v"(fp) : "memory");
        } while (!__all((int)(v >= (unsigned)t)));
      }
      __syncthreads();
      if (tid < 512) {
        f32x4 d0, d1;
        asm volatile("global_load_dwordx4 %0, %2, off sc0\n\t"
                     "global_load_dwordx4 %1, %3, off sc0\n\t"
                     "s_waitcnt vmcnt(0)"
                     : "=v"(d0), "=v"(d1) : "v"(spA0), "v"(spA1) : "memory");
        *reinterpret_cast<f32x4*>(ld0) = d0;
        *reinterpret_cast<f32x4*>(ld1) = d1;
      }
    }
    float grA0 = gpA0[0], gzA0 = gpA0[512], gnA0 = gpA0[1024]; gpA0 += 49152;
    float grA1 = 0.f, gzA1 = 0.f, gnA1 = 0.f;
    if (s1) { grA1 = gpA1[0]; gzA1 = gpA1[512]; gnA1 = gpA1[1024]; }
    gpA1 += 49152;
    if (tid < 512) { spA0 += 1024; spA1 += 1024; }
    __syncthreads();   // Ah(A) ready
    {
      f32x4 a0 = {}, a1 = {};
#pragma unroll
      for (int kt = 0; kt < 8; ++kt) {
        bf16x8 a = *reinterpret_cast<const bf16x8*>(
            (const char*)Ah + r15 * 1024 + ((kt * 64 + cbyte) ^ ((r15 & 7) << 4)));
        a0 = __builtin_amdgcn_mfma_f32_16x16x32_bf16(a, barr[0][kt], a0, 0, 0, 0);
        a1 = __builtin_amdgcn_mfma_f32_16x16x32_bf16(a, barr[1][kt], a1, 0, 0, 0);
      }
#pragma unroll
      for (int q = 0; q < 4; ++q) {
        gh[gate][sig][brow + q][ucol] = a0[q];
        gh[gate][sig][brow + q][ucol + 16] = a1[q];
      }
    }
    __syncthreads();   // gh(A) ready
    {
      float hr = gh[0][0][bl0][u] + gh[0][1][bl0][u] + bb0;
      float hz = gh[1][0][bl0][u] + gh[1][1][bl0][u] + bb1;
      float hn = gh[2][0][bl0][u] + gh[2][1][bl0][u] + bb2;
      float r = 1.f / (1.f + __builtin_amdgcn_exp2f(K1 * (grA0 + hr)));
      float z = 1.f / (1.f + __builtin_amdgcn_exp2f(K1 * (gzA0 + hz)));
      float x = gnA0 + r * hn;
      float th = 1.f - 2.f / (1.f + __builtin_amdgcn_exp2f(K2 * x));
      float hnew = th + z * (hpA0 - th);
      hpA0 = hnew;
      asm volatile("global_store_short %0, %1, off sc0"
                   :: "v"(hsA0), "v"((unsigned)f2bf(hnew)) : "memory");
      hsA0 += 512;
    }
    if (s1) {
      float hr = gh[0][0][bl1][u] + gh[0][1][bl1][u] + bb0;
      float hz = gh[1][0][bl1][u] + gh[1][1][bl1][u] + bb1;
      float hn = gh[2][0][bl1][u] + gh[2][1][bl1][u] + bb2;
      float r = 1.f / (1.f + __builtin_amdgcn_exp2f(K1 * (grA1 + hr)));
      float z = 1.f / (1.f + __builtin_amdgcn_exp2f(K1 * (gzA1 + hz)));
      float x = gnA1 + r * hn;
      float th = 1.f - 2.f / (1.f + __builtin_amdgcn_exp2f(K2 * x));
      float hnew = th + z * (hpA1 - th);
      hpA1 = hnew;
      asm volatile("global_store_short %0, %1, off sc0"
                   :: "v"(hsA1), "v"((unsigned)f2bf(hnew)) : "memory");
    }
    hsA1 += 512;
    asm volatile("s_waitcnt vmcnt(0)" ::: "memory");
    __syncthreads();   // all HS(A) stored
    if (tid == 704) {
      unsigned ph = (unsigned)(t + 1);
      asm volatile("global_store_dword %0, %1, off sc0\n\ts_waitcnt vmcnt(0)"
                   :: "v"(flags + g * 16), "v"(ph) : "memory");
    }
    // ================= HALF B (b 16-31) =================
    if (t == 0) {
      if (tid < 256) {
#pragma unroll
        for (int l = 0; l < 4; ++l) {
          int n = l * 256 + tid; int row = n >> 6; int i = n & 63;
          const float* sp = eh + ((16 + row) * 512 + i * 8);
          float4 aa = *reinterpret_cast<const float4*>(sp);
          float4 bb = *reinterpret_cast<const float4*>(sp + 4);
          u16x8v o8;
          o8[0] = f2bf(aa.x); o8[1] = f2bf(aa.y); o8[2] = f2bf(aa.z); o8[3] = f2bf(aa.w);
          o8[4] = f2bf(bb.x); o8[5] = f2bf(bb.y); o8[6] = f2bf(bb.z); o8[7] = f2bf(bb.w);
          *reinterpret_cast<u16x8v*>((char*)Ah + row * 1024 + ((i * 16) ^ ((row & 7) << 4))) = o8;
        }
      }
    } else {
      if (wave == 0) {
        const unsigned* fp = flags + 128 + (lane & 7) * 16;
        unsigned v;
        do {
          asm volatile("global_load_dword %0, %1, off sc0\n\ts_waitcnt vmcnt(0)"
                       : "=v"(v) : "v"(fp) : "memory");
        } while (!__all((int)(v >= (unsigned)t)));
      }
      __syncthreads();
      if (tid < 512) {
        f32x4 d0, d1;
        asm volatile("global_load_dwordx4 %0, %2, off sc0\n\t"
                     "global_load_dwordx4 %1, %3, off sc0\n\t"
                     "s_waitcnt vmcnt(0)"
                     : "=v"(d0), "=v"(d1) : "v"(spB0), "v"(spB1) : "memory");
        *reinterpret_cast<f32x4*>(ld0) = d0;
        *reinterpret_cast<f32x4*>(ld1) = d1;
      }
    }
    float grB0 = gpB0[0], gzB0 = gpB0[512], gnB0 = gpB0[1024]; gpB0 += 49152;
    float grB1 = 0.f, gzB1 = 0.f, gnB1 = 0.f;
    if (s1) { grB1 = gpB1[0]; gzB1 = gpB1[512]; gnB1 = gpB1[1024]; }
    gpB1 += 49152;
    if (tid < 512) { spB0 += 1024; spB1 += 1024; }
    __syncthreads();   // Ah(B) ready
    {
      f32x4 a0 = {}, a1 = {};
#pragma unroll
      for (int kt = 0; kt < 8; ++kt) {
        bf16x8 a = *reinterpret_cast<const bf16x8*>(
            (const char*)Ah + r15 * 1024 + ((kt * 64 + cbyte) ^ ((r15 & 7) << 4)));
        a0 = __builtin_amdgcn_mfma_f32_16x16x32_bf16(a, barr[0][kt], a0, 0, 0, 0);
        a1 = __builtin_amdgcn_mfma_f32_16x16x32_bf16(a, barr[1][kt], a1, 0, 0, 0);
      }
#pragma unroll
      for (int q = 0; q < 4; ++q) {
        gh[gate][sig][brow + q][ucol] = a0[q];
        gh[gate][sig][brow + q][ucol + 16] = a1[q];
      }
    }
    __syncthreads();   // gh(B) ready
    {
      float hr = gh[0][0][bl0][u] + gh[0][1][bl0][u] + bb0;
      float hz = gh[1][0][bl0][u] + gh[1][1][bl0][u] + bb1;
      float hn = gh[2][0][bl0][u] + gh[2][1][bl0][u] + bb2;
      float r = 1.f / (1.f + __builtin_amdgcn_exp2f(K1 * (grB0 + hr)));
      float z = 1.f / (1.f + __builtin_amdgcn_exp2f(K1 * (gzB0 + hz)));
      float x = gnB0 + r * hn;
      float th = 1.f - 2.f / (1.f + __builtin_amdgcn_exp2f(K2 * x));
      float hnew = th + z * (hpB0 - th);
      hpB0 = hnew;
      asm volatile("global_store_short %0, %1, off sc0"
                   :: "v"(hsB0), "v"((unsigned)f2bf(hnew)) : "memory");
      hsB0 += 512;
    }
    if (s1) {
      float hr = gh[0][0][bl1][u] + gh[0][1][bl1][u] + bb0;
      float hz = gh[1][0][bl1][u] + gh[1][1][bl1][u] + bb1;
      float hn = gh[2][0][bl1][u] + gh[2][1][bl1][u] + bb2;
      float r = 1.f / (1.f + __builtin_amdgcn_exp2f(K1 * (grB1 + hr)));
      float z = 1.f / (1.f + __builtin_amdgcn_exp2f(K1 * (gzB1 + hz)));
      float x = gnB1 + r * hn;
      float th = 1.f - 2.f / (1.f + __builtin_amdgcn_exp2f(K2 * x));
      float hnew = th + z * (hpB1 - th);
      hpB1 = hnew;
      asm volatile("global_store_short %0, %1, off sc0"
                   :: "v"(hsB1), "v"((unsigned)f2bf(hnew)) : "memory");
    }
    hsB1 += 512;
    asm volatile("s_waitcnt vmcnt(0)" ::: "memory");
    __syncthreads();   // all HS(B) stored
    if (tid == 704) {
      unsigned ph = (unsigned)(t + 1);
      asm volatile("global_store_dword %0, %1, off sc0\n\ts_waitcnt vmcnt(0)"
                   :: "v"(flags + 128 + g * 16), "v"(ph) : "memory");
    }
  }
  // confirm everyone finished all polls, then write back dirty L2 (flags + HS) to LLC
  if (wave == 0) {
    const unsigned* fp = flags + 128 + (lane & 7) * 16;
    unsigned v;
    do {
      asm volatile("global_load_dword %0, %1, off sc0\n\ts_waitcnt vmcnt(0)"
                   : "=v"(v) : "v"(fp) : "memory");
    } while (!__all((int)(v >= 64u)));
  }
  __syncthreads();
  if (tid == 0) asm volatile("buffer_wbl2 sc1\n\ts_waitcnt vmcnt(0)" ::: "memory");
  // decoder_hidden output
  outH[bA0 * 512 + j0 + u] = hpA0;
  if (s1) outH[bA1 * 512 + j0 + u] = hpA1;
  outH[bB0 * 512 + j0 + u] = hpB0;
  if (s1) outH[bB1 * 512 + j0 + u] = hpB1;
}

// ---------------- log_softmax: bf16 logits (aliased in d_out row slot) -> f32 ----------------
extern "C" __global__ void __launch_bounds__(512)
k_lsm_b(const u16* __restrict__ LGbase, float* __restrict__ P) {
  extern __shared__ u16 srb[];
  __shared__ float red[8];
  const u16* LG = LGbase + (long)blockIdx.x * LDC2;
  float* out = P + (long)blockIdx.x * 32000;
  int tid = threadIdx.x, wave = tid >> 6, lane = tid & 63;
  float mx = -INFINITY;
  for (int i = tid; i < 4000; i += 512) {
    u16x8v v = reinterpret_cast<const u16x8v*>(LG)[i];
    reinterpret_cast<u16x8v*>(srb)[i] = v;
#pragma unroll
    for (int e = 0; e < 8; ++e) mx = fmaxf(mx, bf2f(v[e]));
  }
#pragma unroll
  for (int off = 32; off; off >>= 1) mx = fmaxf(mx, __shfl_down(mx, off, 64));
  if (lane == 0) red[wave] = mx;
  __syncthreads();
  if (tid == 0) {
    float m = red[0];
#pragma unroll
    for (int w = 1; w < 8; ++w) m = fmaxf(m, red[w]);
    red[0] = m;
  }
  __syncthreads();
  mx = red[0];
  __syncthreads();
  float sm = 0.f;
  for (int i = tid; i < 4000; i += 512) {
    u16x8v v = reinterpret_cast<const u16x8v*>(srb)[i];
#pragma unroll
    for (int e = 0; e < 8; ++e) sm += __expf(bf2f(v[e]) - mx);
  }
#pragma unroll
  for (int off = 32; off; off >>= 1) sm += __shfl_down(sm, off, 64);
  if (lane == 0) red[wave] = sm;
  __syncthreads();
  if (tid == 0) {
    float s = 0.f;
#pragma unroll
    for (int w = 0; w < 8; ++w) s += red[w];
    red[0] = mx + __logf(s);
  }
  __syncthreads();
  float L = red[0];
  for (int i = tid; i < 4000; i += 512) {
    u16x8v v = reinterpret_cast<const u16x8v*>(srb)[i];
    float4 o1, o2;
    o1.x = bf2f(v[0]) - L; o1.y = bf2f(v[1]) - L; o1.z = bf2f(v[2]) - L; o1.w = bf2f(v[3]) - L;
    o2.x = bf2f(v[4]) - L; o2.y = bf2f(v[5]) - L; o2.z = bf2f(v[6]) - L; o2.w = bf2f(v[7]) - L;
    reinterpret_cast<float4*>(out + (long)i * 8)[0] = o1;
    reinterpret_cast<float4*>(out + (long)i * 8)[1] = o2;
  }
}

extern "C" void kernel_launch(void* const* d_in, const int* in_sizes, int n_in,
                              void* d_out, int out_size, void* d_ws, size_t ws_size,
                              hipStream_t stream) {
  (void)in_sizes; (void)n_in; (void)out_size;
  const float* enc_hid = (const float*)d_in[1];
  const int*   tgt     = (const int*)d_in[2];
  const float* emb     = (const float*)d_in[3];
  const float* W_ih    = (const float*)d_in[4];
  const float* W_hh    = (const float*)d_in[5];
  const float* b_ih    = (const float*)d_in[6];
  const float* b_hh    = (const float*)d_in[7];
  const float* W_out   = (const float*)d_in[8];
  const float* b_out   = (const float*)d_in[9];
  float* out = (float*)d_out;
  char* ws = (char*)d_ws;
  if (ws_size < (size_t)WS_NEED) return;

  u16* X        = (u16*)(ws + OFF_X);
  u16* Wih      = (u16*)(ws + OFF_WIH);
  u16* Whh      = (u16*)(ws + OFF_WHH);
  u16* Wout     = (u16*)(ws + OFF_WOUT);
  float* gi     = (float*)(ws + OFF_GI);
  u16* HS       = (u16*)(ws + OFF_HS);
  unsigned* flg = (unsigned*)(ws + OFF_FLG);
  unsigned* ev  = (unsigned*)(ws + OFF_EV);
  u16* LG       = (u16*)d_out;

  hipFuncSetAttribute(reinterpret_cast<const void*>(k_lsm_b),
                      hipFuncAttributeMaxDynamicSharedMemorySize, 65536);

  k_cast<<<96, 256, 0, stream>>>(W_ih, Wih, 1536 * 256 / 4);
  k_cast<<<192, 256, 0, stream>>>(W_hh, Whh, 1536 * 512 / 4);
  k_cast<<<2048, 256, 0, stream>>>(W_out, Wout, 32000 * 512 / 4);
  k_embed<<<256, 256, 0, stream>>>(emb, tgt, X);
  k_init<<<1, 256, 0, stream>>>(flg, ev);
  k_gemm_t<false><<<(1536 / 128) * (2048 / 128), 256, 0, stream>>>(
      X, Wih, b_ih, gi, nullptr, 2048, 1536, 256, 0);
  k_gru7<<<64, 768, 0, stream>>>(gi, Whh, b_hh, enc_hid, HS, out + BTV, flg, ev);
  k_gemm_t<true><<<(32000 / 128) * (2048 / 128), 256, 0, stream>>>(
      HS, Wout, b_out, nullptr, LG, 2048, 32000, 512, LDC2);
  k_lsm_b<<<2048, 512, 64000, stream>>>(LG, out);
}

// Round 9
// 489.816 us; speedup vs baseline: 19115.2218x; 19115.2218x over previous
//
#include <hip/hip_runtime.h>
#include <hip/hip_bf16.h>
#include <math.h>

// GRU decoder: embed+relu -> gi GEMM (2-phase dbuf) -> same-XCD hidden-split GRU
// with half-batch pipelining (system-scope flags, L2 data) -> vocab projection
// (2-phase dbuf, bf16 logits aliased into d_out) -> log_softmax.

typedef __bf16 bf16x8 __attribute__((ext_vector_type(8)));
typedef float  f32x4  __attribute__((ext_vector_type(4)));
typedef unsigned short u16;
typedef u16 u16x8v __attribute__((ext_vector_type(8)));
typedef u16 u16x4v __attribute__((ext_vector_type(4)));

#define BTV (32L * 64 * 32000)
#define LDC2 64000L   // bf16 logit row stride inside d_out (half of a 128000B f32 row slot)

// ---- ws layout (bytes) ----
#define OFF_X    (0L)
#define SZ_X     (2048L * 256 * 2)
#define OFF_WIH  (OFF_X + SZ_X)
#define SZ_WIH   (1536L * 256 * 2)
#define OFF_WHH  (OFF_WIH + SZ_WIH)
#define SZ_WHH   (1536L * 512 * 2)
#define OFF_WOUT (OFF_WHH + SZ_WHH)
#define SZ_WOUT  (32000L * 512 * 2)
#define OFF_GI   (OFF_WOUT + SZ_WOUT)
#define SZ_GI    (2048L * 1536 * 4)
#define OFF_HS   (OFF_GI + SZ_GI)
#define SZ_HS    (2048L * 512 * 2)
#define OFF_FLG  (OFF_HS + SZ_HS)
#define SZ_FLG   (1024L)
#define OFF_EV   (OFF_FLG + SZ_FLG)
#define SZ_EV    (64L)
#define WS_NEED  (OFF_EV + SZ_EV)

__device__ __forceinline__ u16 f2bf(float f) {
  union { float f; unsigned u; } a; a.f = f;
  unsigned r = a.u + 0x7fffu + ((a.u >> 16) & 1u);
  return (u16)(r >> 16);
}

__device__ __forceinline__ float bf2f(u16 u) {
  union { unsigned u; float f; } a; a.u = ((unsigned)u) << 16;
  return a.f;
}

__device__ __forceinline__ void gload16(const void* g, void* l) {
  __builtin_amdgcn_global_load_lds(
      (const __attribute__((address_space(1))) unsigned int*)g,
      (__attribute__((address_space(3))) unsigned int*)l, 16, 0, 0);
}

// ---------------- cast f32 -> bf16 ----------------
extern "C" __global__ void k_cast(const float* __restrict__ s, u16* __restrict__ d, int n4) {
  int i = blockIdx.x * blockDim.x + threadIdx.x;
  int st = gridDim.x * blockDim.x;
  for (; i < n4; i += st) {
    float4 v = reinterpret_cast<const float4*>(s)[i];
    u16x4v o; o.x = f2bf(v.x); o.y = f2bf(v.y); o.z = f2bf(v.z); o.w = f2bf(v.w);
    reinterpret_cast<u16x4v*>(d)[i] = o;
  }
}

// ---------------- embed + relu -> X[t*32+b][256] bf16 ----------------
extern "C" __global__ void k_embed(const float* __restrict__ emb, const int* __restrict__ tgt,
                                   u16* __restrict__ X) {
  int idx = blockIdx.x * 256 + threadIdx.x;
  int row = idx >> 5;
  int c8  = (idx & 31) << 3;
  int t = row >> 5, b = row & 31;
  int token = (t == 0) ? 0 : tgt[b * 64 + t - 1];
  const float* e = emb + (long)token * 256 + c8;
  u16x8v o;
#pragma unroll
  for (int i = 0; i < 8; ++i) { float v = e[i]; o[i] = f2bf(v > 0.f ? v : 0.f); }
  *reinterpret_cast<u16x8v*>(X + (long)row * 256 + c8) = o;
}

// ---------------- flags + election vars init ----------------
extern "C" __global__ void k_init(unsigned* flags, unsigned* evars) {
  int i = threadIdx.x;
  if (i < 256) {
    unsigned z = 0u;
    asm volatile("global_store_dword %0, %1, off sc0 sc1"
                 :: "v"(flags + i), "v"(z) : "memory");
  }
  if (i < 10) atomicExch(&evars[i], i == 8 ? 0xFFFFFFFFu : 0u);
}

// ---------------- bf16 MFMA GEMM, C = A*B^T + bias, 2-phase LDS double-buffer ----------------
template <bool BF16OUT>
__global__ void __launch_bounds__(256)
k_gemm_t(const u16* __restrict__ A, const u16* __restrict__ B,
         const float* __restrict__ bias, float* __restrict__ C,
         u16* __restrict__ C2, int M, int N, int K, long ldc2) {
  __shared__ u16 At[2][4096];
  __shared__ u16 Bt[2][4096];
  int mt = M >> 7;
  int bn = blockIdx.x / mt, bm = blockIdx.x % mt;
  int tid = threadIdx.x, wave = tid >> 6, lane = tid & 63;
  int wr = wave >> 1, wc = wave & 1;
  f32x4 acc[4][4] = {};
  const u16* ga = A + (long)(bm * 128 + wave * 32 + (lane >> 2)) * K + ((lane & 3) << 3);
  const u16* gb = B + (long)(bn * 128 + wave * 32 + (lane >> 2)) * K + ((lane & 3) << 3);
  long k16 = 16L * K;
  {
    u16* la0 = &At[0][wave * 1024]; u16* lb0 = &Bt[0][wave * 1024];
    gload16(ga, la0); gload16(ga + k16, la0 + 512);
    gload16(gb, lb0); gload16(gb + k16, lb0 + 512);
  }
  asm volatile("s_waitcnt vmcnt(0)" ::: "memory");
  __syncthreads();
  int cur = 0;
  for (int k0 = 0; k0 < K; k0 += 32) {
    if (k0 + 32 < K) {
      int nb = cur ^ 1;
      u16* la0 = &At[nb][wave * 1024]; u16* lb0 = &Bt[nb][wave * 1024];
      gload16(ga + k0 + 32, la0); gload16(ga + k16 + k0 + 32, la0 + 512);
      gload16(gb + k0 + 32, lb0); gload16(gb + k16 + k0 + 32, lb0 + 512);
    }
    bf16x8 af[4], bfr[4];
#pragma unroll
    for (int mi = 0; mi < 4; ++mi)
      af[mi] = *reinterpret_cast<const bf16x8*>(
          &At[cur][(wr * 64 + mi * 16 + (lane & 15)) * 32 + ((lane >> 4) << 3)]);
#pragma unroll
    for (int ni = 0; ni < 4; ++ni)
      bfr[ni] = *reinterpret_cast<const bf16x8*>(
          &Bt[cur][(wc * 64 + ni * 16 + (lane & 15)) * 32 + ((lane >> 4) << 3)]);
#pragma unroll
    for (int mi = 0; mi < 4; ++mi)
#pragma unroll
      for (int ni = 0; ni < 4; ++ni)
        acc[mi][ni] = __builtin_amdgcn_mfma_f32_16x16x32_bf16(af[mi], bfr[ni], acc[mi][ni], 0, 0, 0);
    asm volatile("s_waitcnt vmcnt(0)" ::: "memory");
    __syncthreads();
    cur ^= 1;
  }
  int rb = bm * 128 + wr * 64 + ((lane >> 4) << 2);
  int cb = bn * 128 + wc * 64 + (lane & 15);
#pragma unroll
  for (int mi = 0; mi < 4; ++mi)
#pragma unroll
    for (int ni = 0; ni < 4; ++ni) {
      int col = cb + ni * 16;
      float bv = bias[col];
#pragma unroll
      for (int q = 0; q < 4; ++q) {
        int rr = rb + mi * 16 + q;
        if (BF16OUT) C2[(long)rr * ldc2 + col] = f2bf(acc[mi][ni][q] + bv);
        else         C[(long)rr * N + col] = acc[mi][ni][q] + bv;
      }
    }
}

// ---------------- same-XCD hidden-split GRU, half-batch pipelined ----------------
// 64 blocks launched; leader election picks one XCD, first 8 claimants work.
// Per step: two half-batch phases (b 0-15, 16-31); each half's flag handoff hides
// under the other half's compute. Flags: sc0 sc1 (system scope — polls MUST bypass
// L1; sc0-only polls hit stale L1 = R8's 1000x pathology). Data: sc0.
extern "C" __global__ void __launch_bounds__(768, 1)
k_gru8(const float* __restrict__ gi, const u16* __restrict__ Whh,
       const float* __restrict__ bhh, const float* __restrict__ eh,
       u16* __restrict__ HS, float* __restrict__ outH,
       unsigned* flags, unsigned* evars) {
  __shared__ u16 Ah[16 * 512];          // swizzled half-batch h tile (16 KB, reused A/B)
  __shared__ float gh[3][2][16][66];    // gate partials (reused A/B)
  __shared__ int role_s;
  int tid = threadIdx.x, wave = tid >> 6, lane = tid & 63;
  if (tid == 0) {
    unsigned xcc;
    asm volatile("s_getreg_b32 %0, hwreg(20, 0, 32)" : "=s"(xcc));
    xcc &= 7u;
    unsigned arr = atomicAdd(&evars[xcc], 1u);
    if (arr == 7u) atomicCAS(&evars[8], 0xFFFFFFFFu, xcc);
    unsigned L = 0xFFFFFFFFu;
    for (int it = 0; it < (1 << 24) && L == 0xFFFFFFFFu; ++it) {
      asm volatile("global_load_dword %0, %1, off sc0 sc1\n\ts_waitcnt vmcnt(0)"
                   : "=v"(L) : "v"(evars + 8) : "memory");
    }
    int role = -1;
    if (L == xcc) {
      unsigned c = atomicAdd(&evars[9], 1u);
      if (c < 8u) role = (int)c;
    }
    role_s = role;
  }
  __syncthreads();
  int g = role_s;
  if (g < 0) return;
  int j0 = g * 64;
  int gate = wave >> 2, uh = (wave >> 1) & 1, sig = wave & 1;
  bf16x8 barr[2][8];
  {
    const u16* wbase = Whh + (long)(gate * 512 + j0 + uh * 32) * 512 + sig * 256;
#pragma unroll
    for (int ut = 0; ut < 2; ++ut)
#pragma unroll
      for (int kt = 0; kt < 8; ++kt)
        barr[ut][kt] = *reinterpret_cast<const bf16x8*>(
            wbase + (long)(ut * 16 + (lane & 15)) * 512 + kt * 32 + ((lane >> 4) << 3));
  }
  int u = tid & 63;
  int bl0 = tid >> 6, bl1 = 12 + bl0;
  bool s1 = tid < 256;
  int bA0 = bl0, bA1 = bl1, bB0 = 16 + bl0, bB1 = 28 + bl0;
  float bb0 = bhh[j0 + u], bb1 = bhh[512 + j0 + u], bb2 = bhh[1024 + j0 + u];
  float hpA0 = eh[bA0 * 512 + j0 + u];
  float hpA1 = s1 ? eh[bA1 * 512 + j0 + u] : 0.f;
  float hpB0 = eh[bB0 * 512 + j0 + u];
  float hpB1 = s1 ? eh[bB1 * 512 + j0 + u] : 0.f;
  const float* gpA0 = gi + (long)bA0 * 1536 + j0 + u;
  const float* gpA1 = gi + (long)bA1 * 1536 + j0 + u;
  const float* gpB0 = gi + (long)bB0 * 1536 + j0 + u;
  const float* gpB1 = gi + (long)bB1 * 1536 + j0 + u;
  u16* hsA0 = HS + (long)bA0 * 64 * 512 + j0 + u;
  u16* hsA1 = HS + (long)bA1 * 64 * 512 + j0 + u;
  u16* hsB0 = HS + (long)bB0 * 64 * 512 + j0 + u;
  u16* hsB1 = HS + (long)bB1 * 64 * 512 + j0 + u;
  char* ld0 = nullptr; char* ld1 = nullptr;
  const char* spA0 = nullptr; const char* spA1 = nullptr;
  const char* spB0 = nullptr; const char* spB1 = nullptr;
  if (tid < 512) {
    int r0 = tid >> 6, i0 = tid & 63, r1 = 8 + r0;
    ld0 = (char*)Ah + r0 * 1024 + ((i0 * 16) ^ ((r0 & 7) << 4));
    ld1 = (char*)Ah + r1 * 1024 + ((i0 * 16) ^ ((r1 & 7) << 4));
    spA0 = (const char*)HS + (long)r0 * 65536 + i0 * 16 - 1024;
    spA1 = (const char*)HS + (long)r1 * 65536 + i0 * 16 - 1024;
    spB0 = spA0 + 16L * 65536;
    spB1 = spA1 + 16L * 65536;
  }
  int r15 = lane & 15;
  int cbyte = sig * 512 + ((lane >> 4) << 4);
  int ucol = uh * 32 + r15;
  int brow = (lane >> 4) << 2;
  const float K1 = -1.44269504f, K2 = 2.88539009f;

  for (int t = 0; t < 64; ++t) {
    // ================= HALF A (b 0-15) =================
    if (t == 0) {
      if (tid < 256) {
#pragma unroll
        for (int l = 0; l < 4; ++l) {
          int n = l * 256 + tid; int row = n >> 6; int i = n & 63;
          const float* sp = eh + (row * 512 + i * 8);
          float4 aa = *reinterpret_cast<const float4*>(sp);
          float4 bb = *reinterpret_cast<const float4*>(sp + 4);
          u16x8v o8;
          o8[0] = f2bf(aa.x); o8[1] = f2bf(aa.y); o8[2] = f2bf(aa.z); o8[3] = f2bf(aa.w);
          o8[4] = f2bf(bb.x); o8[5] = f2bf(bb.y); o8[6] = f2bf(bb.z); o8[7] = f2bf(bb.w);
          *reinterpret_cast<u16x8v*>((char*)Ah + row * 1024 + ((i * 16) ^ ((row & 7) << 4))) = o8;
        }
      }
    } else {
      if (wave == 0) {
        const unsigned* fp = flags + (lane & 7) * 16;
        unsigned v;
        do {
          asm volatile("global_load_dword %0, %1, off sc0 sc1\n\ts_waitcnt vmcnt(0)"
                       : "=v"(v) : "v"(fp) : "memory");
        } while (!__all((int)(v >= (unsigned)t)));
      }
      __syncthreads();
      if (tid < 512) {
        f32x4 d0, d1;
        asm volatile("global_load_dwordx4 %0, %2, off sc0\n\t"
                     "global_load_dwordx4 %1, %3, off sc0\n\t"
                     "s_waitcnt vmcnt(0)"
                     : "=v"(d0), "=v"(d1) : "v"(spA0), "v"(spA1) : "memory");
        *reinterpret_cast<f32x4*>(ld0) = d0;
        *reinterpret_cast<f32x4*>(ld1) = d1;
      }
    }
    float grA0 = gpA0[0], gzA0 = gpA0[512], gnA0 = gpA0[1024]; gpA0 += 49152;
    float grA1 = 0.f, gzA1 = 0.f, gnA1 = 0.f;
    if (s1) { grA1 = gpA1[0]; gzA1 = gpA1[512]; gnA1 = gpA1[1024]; }
    gpA1 += 49152;
    if (tid < 512) { spA0 += 1024; spA1 += 1024; }
    __syncthreads();   // Ah(A) ready
    {
      f32x4 a0 = {}, a1 = {};
#pragma unroll
      for (int kt = 0; kt < 8; ++kt) {
        bf16x8 a = *reinterpret_cast<const bf16x8*>(
            (const char*)Ah + r15 * 1024 + ((kt * 64 + cbyte) ^ ((r15 & 7) << 4)));
        a0 = __builtin_amdgcn_mfma_f32_16x16x32_bf16(a, barr[0][kt], a0, 0, 0, 0);
        a1 = __builtin_amdgcn_mfma_f32_16x16x32_bf16(a, barr[1][kt], a1, 0, 0, 0);
      }
#pragma unroll
      for (int q = 0; q < 4; ++q) {
        gh[gate][sig][brow + q][ucol] = a0[q];
        gh[gate][sig][brow + q][ucol + 16] = a1[q];
      }
    }
    __syncthreads();   // gh(A) ready
    {
      float hr = gh[0][0][bl0][u] + gh[0][1][bl0][u] + bb0;
      float hz = gh[1][0][bl0][u] + gh[1][1][bl0][u] + bb1;
      float hn = gh[2][0][bl0][u] + gh[2][1][bl0][u] + bb2;
      float r = 1.f / (1.f + __builtin_amdgcn_exp2f(K1 * (grA0 + hr)));
      float z = 1.f / (1.f + __builtin_amdgcn_exp2f(K1 * (gzA0 + hz)));
      float x = gnA0 + r * hn;
      float th = 1.f - 2.f / (1.f + __builtin_amdgcn_exp2f(K2 * x));
      float hnew = th + z * (hpA0 - th);
      hpA0 = hnew;
      asm volatile("global_store_short %0, %1, off sc0"
                   :: "v"(hsA0), "v"((unsigned)f2bf(hnew)) : "memory");
      hsA0 += 512;
    }
    if (s1) {
      float hr = gh[0][0][bl1][u] + gh[0][1][bl1][u] + bb0;
      float hz = gh[1][0][bl1][u] + gh[1][1][bl1][u] + bb1;
      float hn = gh[2][0][bl1][u] + gh[2][1][bl1][u] + bb2;
      float r = 1.f / (1.f + __builtin_amdgcn_exp2f(K1 * (grA1 + hr)));
      float z = 1.f / (1.f + __builtin_amdgcn_exp2f(K1 * (gzA1 + hz)));
      float x = gnA1 + r * hn;
      float th = 1.f - 2.f / (1.f + __builtin_amdgcn_exp2f(K2 * x));
      float hnew = th + z * (hpA1 - th);
      hpA1 = hnew;
      asm volatile("global_store_short %0, %1, off sc0"
                   :: "v"(hsA1), "v"((unsigned)f2bf(hnew)) : "memory");
    }
    hsA1 += 512;
    asm volatile("s_waitcnt vmcnt(0)" ::: "memory");
    __syncthreads();   // all HS(A) stored
    if (tid == 704) {
      unsigned ph = (unsigned)(t + 1);
      asm volatile("global_store_dword %0, %1, off sc0 sc1\n\ts_waitcnt vmcnt(0)"
                   :: "v"(flags + g * 16), "v"(ph) : "memory");
    }
    // ================= HALF B (b 16-31) =================
    if (t == 0) {
      if (tid < 256) {
#pragma unroll
        for (int l = 0; l < 4; ++l) {
          int n = l * 256 + tid; int row = n >> 6; int i = n & 63;
          const float* sp = eh + ((16 + row) * 512 + i * 8);
          float4 aa = *reinterpret_cast<const float4*>(sp);
          float4 bb = *reinterpret_cast<const float4*>(sp + 4);
          u16x8v o8;
          o8[0] = f2bf(aa.x); o8[1] = f2bf(aa.y); o8[2] = f2bf(aa.z); o8[3] = f2bf(aa.w);
          o8[4] = f2bf(bb.x); o8[5] = f2bf(bb.y); o8[6] = f2bf(bb.z); o8[7] = f2bf(bb.w);
          *reinterpret_cast<u16x8v*>((char*)Ah + row * 1024 + ((i * 16) ^ ((row & 7) << 4))) = o8;
        }
      }
    } else {
      if (wave == 0) {
        const unsigned* fp = flags + 128 + (lane & 7) * 16;
        unsigned v;
        do {
          asm volatile("global_load_dword %0, %1, off sc0 sc1\n\ts_waitcnt vmcnt(0)"
                       : "=v"(v) : "v"(fp) : "memory");
        } while (!__all((int)(v >= (unsigned)t)));
      }
      __syncthreads();
      if (tid < 512) {
        f32x4 d0, d1;
        asm volatile("global_load_dwordx4 %0, %2, off sc0\n\t"
                     "global_load_dwordx4 %1, %3, off sc0\n\t"
                     "s_waitcnt vmcnt(0)"
                     : "=v"(d0), "=v"(d1) : "v"(spB0), "v"(spB1) : "memory");
        *reinterpret_cast<f32x4*>(ld0) = d0;
        *reinterpret_cast<f32x4*>(ld1) = d1;
      }
    }
    float grB0 = gpB0[0], gzB0 = gpB0[512], gnB0 = gpB0[1024]; gpB0 += 49152;
    float grB1 = 0.f, gzB1 = 0.f, gnB1 = 0.f;
    if (s1) { grB1 = gpB1[0]; gzB1 = gpB1[512]; gnB1 = gpB1[1024]; }
    gpB1 += 49152;
    if (tid < 512) { spB0 += 1024; spB1 += 1024; }
    __syncthreads();   // Ah(B) ready
    {
      f32x4 a0 = {}, a1 = {};
#pragma unroll
      for (int kt = 0; kt < 8; ++kt) {
        bf16x8 a = *reinterpret_cast<const bf16x8*>(
            (const char*)Ah + r15 * 1024 + ((kt * 64 + cbyte) ^ ((r15 & 7) << 4)));
        a0 = __builtin_amdgcn_mfma_f32_16x16x32_bf16(a, barr[0][kt], a0, 0, 0, 0);
        a1 = __builtin_amdgcn_mfma_f32_16x16x32_bf16(a, barr[1][kt], a1, 0, 0, 0);
      }
#pragma unroll
      for (int q = 0; q < 4; ++q) {
        gh[gate][sig][brow + q][ucol] = a0[q];
        gh[gate][sig][brow + q][ucol + 16] = a1[q];
      }
    }
    __syncthreads();   // gh(B) ready
    {
      float hr = gh[0][0][bl0][u] + gh[0][1][bl0][u] + bb0;
      float hz = gh[1][0][bl0][u] + gh[1][1][bl0][u] + bb1;
      float hn = gh[2][0][bl0][u] + gh[2][1][bl0][u] + bb2;
      float r = 1.f / (1.f + __builtin_amdgcn_exp2f(K1 * (grB0 + hr)));
      float z = 1.f / (1.f + __builtin_amdgcn_exp2f(K1 * (gzB0 + hz)));
      float x = gnB0 + r * hn;
      float th = 1.f - 2.f / (1.f + __builtin_amdgcn_exp2f(K2 * x));
      float hnew = th + z * (hpB0 - th);
      hpB0 = hnew;
      asm volatile("global_store_short %0, %1, off sc0"
                   :: "v"(hsB0), "v"((unsigned)f2bf(hnew)) : "memory");
      hsB0 += 512;
    }
    if (s1) {
      float hr = gh[0][0][bl1][u] + gh[0][1][bl1][u] + bb0;
      float hz = gh[1][0][bl1][u] + gh[1][1][bl1][u] + bb1;
      float hn = gh[2][0][bl1][u] + gh[2][1][bl1][u] + bb2;
      float r = 1.f / (1.f + __builtin_amdgcn_exp2f(K1 * (grB1 + hr)));
      float z = 1.f / (1.f + __builtin_amdgcn_exp2f(K1 * (gzB1 + hz)));
      float x = gnB1 + r * hn;
      float th = 1.f - 2.f / (1.f + __builtin_amdgcn_exp2f(K2 * x));
      float hnew = th + z * (hpB1 - th);
      hpB1 = hnew;
      asm volatile("global_store_short %0, %1, off sc0"
                   :: "v"(hsB1), "v"((unsigned)f2bf(hnew)) : "memory");
    }
    hsB1 += 512;
    asm volatile("s_waitcnt vmcnt(0)" ::: "memory");
    __syncthreads();   // all HS(B) stored
    if (tid == 704) {
      unsigned ph = (unsigned)(t + 1);
      asm volatile("global_store_dword %0, %1, off sc0 sc1\n\ts_waitcnt vmcnt(0)"
                   :: "v"(flags + 128 + g * 16), "v"(ph) : "memory");
    }
  }
  // decoder_hidden output
  outH[bA0 * 512 + j0 + u] = hpA0;
  if (s1) outH[bA1 * 512 + j0 + u] = hpA1;
  outH[bB0 * 512 + j0 + u] = hpB0;
  if (s1) outH[bB1 * 512 + j0 + u] = hpB1;
}

// ---------------- log_softmax: bf16 logits (aliased in d_out row slot) -> f32 ----------------
extern "C" __global__ void __launch_bounds__(512)
k_lsm_b(const u16* __restrict__ LGbase, float* __restrict__ P) {
  extern __shared__ u16 srb[];
  __shared__ float red[8];
  const u16* LG = LGbase + (long)blockIdx.x * LDC2;
  float* out = P + (long)blockIdx.x * 32000;
  int tid = threadIdx.x, wave = tid >> 6, lane = tid & 63;
  float mx = -INFINITY;
  for (int i = tid; i < 4000; i += 512) {
    u16x8v v = reinterpret_cast<const u16x8v*>(LG)[i];
    reinterpret_cast<u16x8v*>(srb)[i] = v;
#pragma unroll
    for (int e = 0; e < 8; ++e) mx = fmaxf(mx, bf2f(v[e]));
  }
#pragma unroll
  for (int off = 32; off; off >>= 1) mx = fmaxf(mx, __shfl_down(mx, off, 64));
  if (lane == 0) red[wave] = mx;
  __syncthreads();
  if (tid == 0) {
    float m = red[0];
#pragma unroll
    for (int w = 1; w < 8; ++w) m = fmaxf(m, red[w]);
    red[0] = m;
  }
  __syncthreads();
  mx = red[0];
  __syncthreads();
  float sm = 0.f;
  for (int i = tid; i < 4000; i += 512) {
    u16x8v v = reinterpret_cast<const u16x8v*>(srb)[i];
#pragma unroll
    for (int e = 0; e < 8; ++e) sm += __expf(bf2f(v[e]) - mx);
  }
#pragma unroll
  for (int off = 32; off; off >>= 1) sm += __shfl_down(sm, off, 64);
  if (lane == 0) red[wave] = sm;
  __syncthreads();
  if (tid == 0) {
    float s = 0.f;
#pragma unroll
    for (int w = 0; w < 8; ++w) s += red[w];
    red[0] = mx + __logf(s);
  }
  __syncthreads();
  float L = red[0];
  for (int i = tid; i < 4000; i += 512) {
    u16x8v v = reinterpret_cast<const u16x8v*>(srb)[i];
    float4 o1, o2;
    o1.x = bf2f(v[0]) - L; o1.y = bf2f(v[1]) - L; o1.z = bf2f(v[2]) - L; o1.w = bf2f(v[3]) - L;
    o2.x = bf2f(v[4]) - L; o2.y = bf2f(v[5]) - L; o2.z = bf2f(v[6]) - L; o2.w = bf2f(v[7]) - L;
    reinterpret_cast<float4*>(out + (long)i * 8)[0] = o1;
    reinterpret_cast<float4*>(out + (long)i * 8)[1] = o2;
  }
}

extern "C" void kernel_launch(void* const* d_in, const int* in_sizes, int n_in,
                              void* d_out, int out_size, void* d_ws, size_t ws_size,
                              hipStream_t stream) {
  (void)in_sizes; (void)n_in; (void)out_size;
  const float* enc_hid = (const float*)d_in[1];
  const int*   tgt     = (const int*)d_in[2];
  const float* emb     = (const float*)d_in[3];
  const float* W_ih    = (const float*)d_in[4];
  const float* W_hh    = (const float*)d_in[5];
  const float* b_ih    = (const float*)d_in[6];
  const float* b_hh    = (const float*)d_in[7];
  const float* W_out   = (const float*)d_in[8];
  const float* b_out   = (const float*)d_in[9];
  float* out = (float*)d_out;
  char* ws = (char*)d_ws;
  if (ws_size < (size_t)WS_NEED) return;

  u16* X        = (u16*)(ws + OFF_X);
  u16* Wih      = (u16*)(ws + OFF_WIH);
  u16* Whh      = (u16*)(ws + OFF_WHH);
  u16* Wout     = (u16*)(ws + OFF_WOUT);
  float* gi     = (float*)(ws + OFF_GI);
  u16* HS       = (u16*)(ws + OFF_HS);
  unsigned* flg = (unsigned*)(ws + OFF_FLG);
  unsigned* ev  = (unsigned*)(ws + OFF_EV);
  u16* LG       = (u16*)d_out;

  hipFuncSetAttribute(reinterpret_cast<const void*>(k_lsm_b),
                      hipFuncAttributeMaxDynamicSharedMemorySize, 65536);

  k_cast<<<96, 256, 0, stream>>>(W_ih, Wih, 1536 * 256 / 4);
  k_cast<<<192, 256, 0, stream>>>(W_hh, Whh, 1536 * 512 / 4);
  k_cast<<<2048, 256, 0, stream>>>(W_out, Wout, 32000 * 512 / 4);
  k_embed<<<256, 256, 0, stream>>>(emb, tgt, X);
  k_init<<<1, 256, 0, stream>>>(flg, ev);
  k_gemm_t<false><<<(1536 / 128) * (2048 / 128), 256, 0, stream>>>(
      X, Wih, b_ih, gi, nullptr, 2048, 1536, 256, 0);
  k_gru8<<<64, 768, 0, stream>>>(gi, Whh, b_hh, enc_hid, HS, out + BTV, flg, ev);
  k_gemm_t<true><<<(32000 / 128) * (2048 / 128), 256, 0, stream>>>(
      HS, Wout, b_out, nullptr, LG, 2048, 32000, 512, LDC2);
  k_lsm_b<<<2048, 512, 64000, stream>>>(LG, out);
}